// Round 3
// baseline (148.456 us; speedup 1.0000x reference)
//
#include <hip/hip_runtime.h>

// FWHT of 2^24 float32, output scaled by 1/2^24.
// Two passes over global memory:
//   Pass 1: bits 0-13 (contiguous 16K chunks, 64 KB LDS, reg-blocked 5+5+4)
//   Pass 2: bits 14-23 (1024 r x 16 c tiles over the (r=1024, c=16384) view,
//           64 KB LDS, reg-blocked 5+5), in-place on d_out, applies 1/N.

#define N_LOG2 24
#define CHUNK_LOG2 14           // pass-1 chunk = 16384 elements = 64 KB LDS
#define CHUNK (1 << CHUNK_LOG2)

// XOR swizzle of LDS float index: flips addr bits 2-4 with (row ^ row>>2)&7,
// row = e>>5. Kills the 64-way bank conflicts of the ownership-change phases
// while keeping float4 (16 B) alignment intact. All six LDS phases land at
// <=2 lanes/bank (free per m136).
static __device__ __forceinline__ int swz(int e) {
  return e ^ ((((e >> 5) ^ (e >> 7)) & 7) << 2);
}

static __device__ __forceinline__ void fwht32(float* v) {
#pragma unroll
  for (int h = 1; h < 32; h <<= 1) {
#pragma unroll
    for (int g = 0; g < 32; g += 2 * h) {
#pragma unroll
      for (int k = 0; k < h; ++k) {
        float a = v[g + k], b = v[g + k + h];
        v[g + k] = a + b;
        v[g + k + h] = a - b;
      }
    }
  }
}

static __device__ __forceinline__ void fwht16(float* v) {
#pragma unroll
  for (int h = 1; h < 16; h <<= 1) {
#pragma unroll
    for (int g = 0; g < 16; g += 2 * h) {
#pragma unroll
      for (int k = 0; k < h; ++k) {
        float a = v[g + k], b = v[g + k + h];
        v[g + k] = a + b;
        v[g + k + h] = a - b;
      }
    }
  }
}

// Pass 1: per-block contiguous chunk of 16384 floats; stages over bits 0-13.
__global__ __launch_bounds__(512) void fwht_pass1(const float* __restrict__ in,
                                                  float* __restrict__ out) {
  __shared__ float lds[CHUNK];
  const int t = threadIdx.x;                 // [0, 512)
  const int base = (int)blockIdx.x << CHUNK_LOG2;
  float v[32];

  // Group 0: thread owns contiguous e = 32t .. 32t+31 (bits 0-4).
  const float4* g4 = reinterpret_cast<const float4*>(in + base) + t * 8;
#pragma unroll
  for (int q = 0; q < 8; ++q) {
    float4 f = g4[q];
    v[4 * q + 0] = f.x; v[4 * q + 1] = f.y;
    v[4 * q + 2] = f.z; v[4 * q + 3] = f.w;
  }
  fwht32(v);  // bits 0-4
#pragma unroll
  for (int q = 0; q < 8; ++q) {
    int e = t * 32 + q * 4;
    *reinterpret_cast<float4*>(&lds[swz(e)]) =
        make_float4(v[4 * q], v[4 * q + 1], v[4 * q + 2], v[4 * q + 3]);
  }
  __syncthreads();

  // Group 1: thread owns e = lo + (j<<5) + (hi<<10), j = 0..31 (bits 5-9).
  const int lo = t & 31, hi = t >> 5;        // hi in [0,16)
#pragma unroll
  for (int j = 0; j < 32; ++j) v[j] = lds[swz(lo + (j << 5) + (hi << 10))];
  fwht32(v);  // bits 5-9
#pragma unroll
  for (int j = 0; j < 32; ++j) lds[swz(lo + (j << 5) + (hi << 10))] = v[j];
  __syncthreads();

  // Group 2: thread owns e = f + (jr<<10) for f = t, t+512 (bits 10-13).
#pragma unroll
  for (int b = 0; b < 2; ++b) {
    int f = t + (b << 9);
#pragma unroll
    for (int jr = 0; jr < 16; ++jr) v[b * 16 + jr] = lds[swz(f + (jr << 10))];
  }
  fwht16(v);
  fwht16(v + 16);
#pragma unroll
  for (int b = 0; b < 2; ++b) {
    int f = t + (b << 9);
#pragma unroll
    for (int jr = 0; jr < 16; ++jr) out[base + f + (jr << 10)] = v[b * 16 + jr];
  }
}

// Pass 2: view i = r*16384 + c, r in [0,1024), c in [0,16384). FWHT over r
// (global bits 14-23). Block owns all 1024 r x 16 c; in-place on `io`.
// Safe in-place: all loads precede the barrier, all stores follow, and blocks
// own disjoint columns.
__global__ __launch_bounds__(512) void fwht_pass2(float* __restrict__ io) {
  __shared__ float lds[CHUNK];
  const int t = threadIdx.x;                 // [0, 512)
  const int cbase = (int)blockIdx.x * 16;
  const int c = t & 15, rhi = t >> 4;        // rhi in [0,32)
  float v[32];

  // Group A: thread owns r = rhi*32 + j (r bits 0-4 vary = global bits 14-18).
  // Lanes 0-15 read 16 consecutive floats of one row: 64 B coalesced segments.
#pragma unroll
  for (int j = 0; j < 32; ++j)
    v[j] = io[(rhi * 32 + j) * CHUNK + cbase + c];
  fwht32(v);  // global bits 14-18
#pragma unroll
  for (int j = 0; j < 32; ++j)
    lds[swz((rhi * 32 + j) * 16 + c)] = v[j];
  __syncthreads();

  // Group B: thread owns r = rlo + 32*j (r bits 5-9 vary = global bits 19-23).
  const int c2 = t & 15, rlo = t >> 4;       // rlo in [0,32)
#pragma unroll
  for (int j = 0; j < 32; ++j)
    v[j] = lds[swz((rlo + 32 * j) * 16 + c2)];
  fwht32(v);  // global bits 19-23
  const float s = 1.0f / 16777216.0f;
#pragma unroll
  for (int j = 0; j < 32; ++j)
    io[(rlo + 32 * j) * CHUNK + cbase + c2] = v[j] * s;
}

extern "C" void kernel_launch(void* const* d_in, const int* in_sizes, int n_in,
                              void* d_out, int out_size, void* d_ws, size_t ws_size,
                              hipStream_t stream) {
  const float* in = (const float*)d_in[0];
  float* out = (float*)d_out;
  // N = 2^24: pass 1 -> d_out, pass 2 in-place on d_out.
  fwht_pass1<<<1024, 512, 0, stream>>>(in, out);
  fwht_pass2<<<1024, 512, 0, stream>>>(out);
}

// Round 4
// 132.658 us; speedup vs baseline: 1.1191x; 1.1191x over previous
//
#include <hip/hip_runtime.h>

// FWHT of 2^24 float32, output scaled by 1/2^24.
// Two passes over global memory:
//   Pass 1: bits 0-13 (contiguous 16K chunks, 64 KB LDS, reg-blocked 5+5+4)
//   Pass 2: bits 14-23 over the (r=1024, c=16384) view. v2: 32-column tiles
//           (128 B global segments, vs 64 B in v1 which measured 2.85 TB/s =
//           the 64 B-granularity roofline). 64 KB LDS, exchange done in two
//           512-row halves. In-place on d_out, applies 1/N.

#define N_LOG2 24
#define CHUNK_LOG2 14           // pass-1 chunk = 16384 elements = 64 KB LDS
#define CHUNK (1 << CHUNK_LOG2)

// Pass-1 LDS swizzle: flips addr bits 2-4 with (row ^ row>>2)&7, row = e>>5.
// All pass-1 LDS phases land at <=2 lanes/bank (free per m136); keeps 16 B
// alignment for float4 stores.
static __device__ __forceinline__ int swz(int e) {
  return e ^ ((((e >> 5) ^ (e >> 7)) & 7) << 2);
}

static __device__ __forceinline__ void fwht32(float* v) {
#pragma unroll
  for (int h = 1; h < 32; h <<= 1) {
#pragma unroll
    for (int g = 0; g < 32; g += 2 * h) {
#pragma unroll
      for (int k = 0; k < h; ++k) {
        float a = v[g + k], b = v[g + k + h];
        v[g + k] = a + b;
        v[g + k + h] = a - b;
      }
    }
  }
}

static __device__ __forceinline__ void fwht16(float* v) {
#pragma unroll
  for (int h = 1; h < 16; h <<= 1) {
#pragma unroll
    for (int g = 0; g < 16; g += 2 * h) {
#pragma unroll
      for (int k = 0; k < h; ++k) {
        float a = v[g + k], b = v[g + k + h];
        v[g + k] = a + b;
        v[g + k + h] = a - b;
      }
    }
  }
}

// Pass 1: per-block contiguous chunk of 16384 floats; stages over bits 0-13.
// (measured <46 us, fully coalesced; unchanged from R3)
__global__ __launch_bounds__(512) void fwht_pass1(const float* __restrict__ in,
                                                  float* __restrict__ out) {
  __shared__ float lds[CHUNK];
  const int t = threadIdx.x;                 // [0, 512)
  const int base = (int)blockIdx.x << CHUNK_LOG2;
  float v[32];

  // Group 0: thread owns contiguous e = 32t .. 32t+31 (bits 0-4).
  const float4* g4 = reinterpret_cast<const float4*>(in + base) + t * 8;
#pragma unroll
  for (int q = 0; q < 8; ++q) {
    float4 f = g4[q];
    v[4 * q + 0] = f.x; v[4 * q + 1] = f.y;
    v[4 * q + 2] = f.z; v[4 * q + 3] = f.w;
  }
  fwht32(v);  // bits 0-4
#pragma unroll
  for (int q = 0; q < 8; ++q) {
    int e = t * 32 + q * 4;
    *reinterpret_cast<float4*>(&lds[swz(e)]) =
        make_float4(v[4 * q], v[4 * q + 1], v[4 * q + 2], v[4 * q + 3]);
  }
  __syncthreads();

  // Group 1: thread owns e = lo + (j<<5) + (hi<<10), j = 0..31 (bits 5-9).
  const int lo = t & 31, hi = t >> 5;        // hi in [0,16)
#pragma unroll
  for (int j = 0; j < 32; ++j) v[j] = lds[swz(lo + (j << 5) + (hi << 10))];
  fwht32(v);  // bits 5-9
#pragma unroll
  for (int j = 0; j < 32; ++j) lds[swz(lo + (j << 5) + (hi << 10))] = v[j];
  __syncthreads();

  // Group 2: thread owns e = f + (jr<<10) for f = t, t+512 (bits 10-13).
#pragma unroll
  for (int b = 0; b < 2; ++b) {
    int f = t + (b << 9);
#pragma unroll
    for (int jr = 0; jr < 16; ++jr) v[b * 16 + jr] = lds[swz(f + (jr << 10))];
  }
  fwht16(v);
  fwht16(v + 16);
#pragma unroll
  for (int b = 0; b < 2; ++b) {
    int f = t + (b << 9);
#pragma unroll
    for (int jr = 0; jr < 16; ++jr) out[base + f + (jr << 10)] = v[b * 16 + jr];
  }
}

// Pass 2 v2: view i = r*16384 + c, r in [0,1024), c in [0,16384).
// Block owns a 1024-row x 32-col tile (grid 512). Per global load/store
// instruction a wave touches 2 rows x 128 B contiguous — double the v1
// segment length. Thread t: c = t&31, rgrp = t>>5 in [0,16); owns rows
// rhi = rgrp and rgrp+16 (A phase), rlo = rgrp and rgrp+16 (B phase).
// A->B exchange via 64 KB LDS in two 512-row halves (3 barriers).
// Every LDS phase: lanes sharing a bank = 2 (same c, two rgrp) -> free.
// In-place safe: all loads precede first barrier; stores follow last one;
// blocks own disjoint column ranges.
__global__ __launch_bounds__(512, 4) void fwht_pass2(float* __restrict__ io) {
  __shared__ float lds[CHUNK];               // 16384 floats = 64 KB
  const int t = threadIdx.x;                 // [0, 512)
  const int c = t & 31, rgrp = t >> 5;       // rgrp in [0,16)
  const int cbase = (int)blockIdx.x * 32;
  float v0[32], v1[32], u0[32], u1[32];

  // A: v0[j] = elem(r = rgrp*32 + j), v1[j] = elem(r = (rgrp+16)*32 + j).
#pragma unroll
  for (int j = 0; j < 32; ++j)
    v0[j] = io[(rgrp * 32 + j) * CHUNK + cbase + c];
#pragma unroll
  for (int j = 0; j < 32; ++j)
    v1[j] = io[((rgrp + 16) * 32 + j) * CHUNK + cbase + c];
  fwht32(v0);  // global bits 14-18 (rows 0-511 group)
  fwht32(v1);  // global bits 14-18 (rows 512-1023 group)

  // Half 0: rows r in [0,512) == all of v0. LDS idx = (r)*32 + c.
#pragma unroll
  for (int j = 0; j < 32; ++j)
    lds[rgrp * 1024 + j * 32 + c] = v0[j];   // r = rgrp*32+j
  __syncthreads();
  // B wants u0[j] = elem(r = rgrp + 32j), u1[j] = elem(r = rgrp+16 + 32j).
  // Half 0 supplies j in [0,16): idx = (rlo + 32j)*32 + c.
#pragma unroll
  for (int j = 0; j < 16; ++j)
    u0[j] = lds[rgrp * 32 + j * 1024 + c];
#pragma unroll
  for (int j = 0; j < 16; ++j)
    u1[j] = lds[(rgrp + 16) * 32 + j * 1024 + c];
  __syncthreads();

  // Half 1: rows r in [512,1024) == all of v1. LDS idx = (r-512)*32 + c.
#pragma unroll
  for (int j = 0; j < 32; ++j)
    lds[rgrp * 1024 + j * 32 + c] = v1[j];   // r-512 = rgrp*32+j
  __syncthreads();
  // Half 1 supplies j in [16,32): idx = (rlo + 32(j-16))*32 + c.
#pragma unroll
  for (int j = 16; j < 32; ++j)
    u0[j] = lds[rgrp * 32 + (j - 16) * 1024 + c];
#pragma unroll
  for (int j = 16; j < 32; ++j)
    u1[j] = lds[(rgrp + 16) * 32 + (j - 16) * 1024 + c];

  fwht32(u0);  // global bits 19-23
  fwht32(u1);
  const float s = 1.0f / 16777216.0f;
#pragma unroll
  for (int j = 0; j < 32; ++j)
    io[(rgrp + 32 * j) * CHUNK + cbase + c] = u0[j] * s;
#pragma unroll
  for (int j = 0; j < 32; ++j)
    io[(rgrp + 16 + 32 * j) * CHUNK + cbase + c] = u1[j] * s;
}

extern "C" void kernel_launch(void* const* d_in, const int* in_sizes, int n_in,
                              void* d_out, int out_size, void* d_ws, size_t ws_size,
                              hipStream_t stream) {
  const float* in = (const float*)d_in[0];
  float* out = (float*)d_out;
  // N = 2^24: pass 1 -> d_out, pass 2 in-place on d_out.
  fwht_pass1<<<1024, 512, 0, stream>>>(in, out);
  fwht_pass2<<<512, 512, 0, stream>>>(out);
}